// Round 1
// baseline (414.130 us; speedup 1.0000x reference)
//
#include <hip/hip_runtime.h>

// out = (x^2) * 0.1, fp32 elementwise. N = 64*1024*1024 = 67108864.
// Memory-bound: 536 MB total HBM traffic -> ~85 us floor at 6.3 TB/s.
// float4 vectorized (16 B/lane coalesced), one float4 per thread.

__global__ void poly_sq_scale_v4(const float4* __restrict__ x,
                                 float4* __restrict__ out,
                                 int n4) {
    int i = blockIdx.x * blockDim.x + threadIdx.x;
    if (i < n4) {
        float4 v = x[i];
        float4 r;
        r.x = v.x * v.x * 0.1f;
        r.y = v.y * v.y * 0.1f;
        r.z = v.z * v.z * 0.1f;
        r.w = v.w * v.w * 0.1f;
        out[i] = r;
    }
}

// Tail handler for N not divisible by 4 (not expected here, but safe).
__global__ void poly_sq_scale_tail(const float* __restrict__ x,
                                   float* __restrict__ out,
                                   int start, int n) {
    int i = start + blockIdx.x * blockDim.x + threadIdx.x;
    if (i < n) {
        float v = x[i];
        out[i] = v * v * 0.1f;
    }
}

extern "C" void kernel_launch(void* const* d_in, const int* in_sizes, int n_in,
                              void* d_out, int out_size, void* d_ws, size_t ws_size,
                              hipStream_t stream) {
    const float* x = (const float*)d_in[0];
    float* out = (float*)d_out;
    int n = out_size;

    int n4 = n / 4;
    if (n4 > 0) {
        const int block = 256;
        int grid = (n4 + block - 1) / block;
        poly_sq_scale_v4<<<grid, block, 0, stream>>>(
            (const float4*)x, (float4*)out, n4);
    }
    int tail_start = n4 * 4;
    int tail = n - tail_start;
    if (tail > 0) {
        poly_sq_scale_tail<<<1, 64, 0, stream>>>(x, out, tail_start, n);
    }
}